// Round 16
// baseline (283.994 us; speedup 1.0000x reference)
//
#include <hip/hip_runtime.h>
#include <hip/hip_bf16.h>
#include <math.h>

#define N_   1024
#define S_   256
#define D_   256
#define C_   256
#define R_   64
#define CLS_ 1000
#define INV16 0.0625f

typedef unsigned short ushortT;
typedef unsigned int uint32;
typedef short bf8 __attribute__((ext_vector_type(8)));
typedef float f4 __attribute__((ext_vector_type(4)));

static __device__ __forceinline__ float bf2f(uint32 u){
  return __uint_as_float(u << 16);
}
static __device__ __forceinline__ ushortT f2bf(float f){
  uint32 x = __float_as_uint(f);
  uint32 r = x + 0x7FFFu + ((x >> 16) & 1u);
  return (ushortT)(r >> 16);
}
static __device__ __forceinline__ uint32 packbf(float a, float b){
  return ((uint32)f2bf(b) << 16) | (uint32)f2bf(a);
}
static __device__ __forceinline__ float wred_max(float v){
  for (int o = 32; o; o >>= 1) v = fmaxf(v, __shfl_xor(v, o));
  return v;
}
static __device__ __forceinline__ float wred_sum(float v){
  for (int o = 32; o; o >>= 1) v += __shfl_xor(v, o);
  return v;
}
// swizzled byte offset inside a [rows][256]-bf16 LDS tile (row stride 512B)
static __device__ __forceinline__ int swz(int row, int colbyte){
  return row*512 + ((colbyte & ~15) ^ ((row & 7) << 4)) + (colbyte & 15);
}
// fragment-ready packed index for a [rows x 256] matrix, 16-row frags, K-step 32
static __device__ __forceinline__ int pkidx(int row, int col, int nfrag){
  int ks = col >> 5, hi = (col >> 3) & 3, e = col & 7;
  int frag = row >> 4, l15p = row & 15;
  return ((ks*nfrag + frag)*64 + hi*16 + l15p)*8 + e;
}
// async HBM->LDS, 16B per lane; LDS dest = uniform base + lane*16
static __device__ __forceinline__ void gload_lds16(const float* src, float* dst){
  __builtin_amdgcn_global_load_lds(
      (const __attribute__((address_space(1))) unsigned int*)src,
      (__attribute__((address_space(3))) unsigned int*)dst, 16, 0, 0);
}
// read 8 consecutive fp32 from XOR-chunk-permuted LDS row, convert to bf8
static __device__ __forceinline__ bf8 kf_read(const float* buf, int row, int c0){
  int x = row & 7;
  const char* base = (const char*)buf + row*1024;
  float4 fa = *(const float4*)(base + ((c0    ) ^ x)*16);
  float4 fb = *(const float4*)(base + ((c0 + 1) ^ x)*16);
  union { bf8 v; uint32 u[4]; } t;
  t.u[0] = packbf(fa.x, fa.y); t.u[1] = packbf(fa.z, fa.w);
  t.u[2] = packbf(fb.x, fb.y); t.u[3] = packbf(fb.z, fb.w);
  return t.v;
}

// ---------------- K0: weight prep + MT = cb @ rcb^T ---------------------------
__global__ __launch_bounds__(256) void k0(const float* __restrict__ cb,
    const float* __restrict__ rcb, const float* __restrict__ Wc,
    const float* __restrict__ Wr, ushortT* __restrict__ a1pk,
    ushortT* __restrict__ Wcr_bf, float* __restrict__ MT_f32,
    ushortT* __restrict__ mtpk)
{
  __shared__ float rl[D_];
  int bid = blockIdx.x, t = threadIdx.x;
  int gtid = bid*256 + t;
  int stride = gridDim.x*256;
  for (int e = gtid; e < (C_ + R_)*D_; e += stride){
    int row = e >> 8, col = e & 255;
    float v = (row < C_) ? cb[e] : rcb[e - C_*D_];
    a1pk[pkidx(row, col, 20)] = f2bf(v);
  }
  for (int e = gtid; e < CLS_*D_; e += stride) Wcr_bf[e] = f2bf(Wc[e]);
  for (int e = gtid; e < D_*D_; e += stride)  Wcr_bf[CLS_*D_ + e] = f2bf(Wr[e]);
  for (int e = gtid; e < 24*D_; e += stride)  Wcr_bf[1256*D_ + e] = 0;

  if (bid < R_){
    rl[t] = rcb[bid*D_ + t];
    __syncthreads();
    float acc = 0.f;
    const float* crow = cb + t*D_;
    #pragma unroll 8
    for (int k = 0; k < D_; k += 4){
      float4 w = *(const float4*)(crow + k);
      acc += w.x*rl[k] + w.y*rl[k+1] + w.z*rl[k+2] + w.w*rl[k+3];
    }
    MT_f32[bid*C_ + t] = acc;
    mtpk[pkidx(bid, t, 4)] = f2bf(acc);
  }
}

// ---------------- K1: per-query pass, batched x4 ------------------------------
#define G4 4
__global__ __launch_bounds__(256) void k1(const float* __restrict__ q,
    const float* __restrict__ cb, const float* __restrict__ rcb,
    const float* __restrict__ Wq, const float* __restrict__ MT_f32,
    float* __restrict__ cw_ws, float* __restrict__ rcw_ws)
{
  __shared__ float qv[G4][D_], qp[G4][D_], cwl[G4][C_];
  __shared__ float redA[G4][4], redB2[G4][4];
  int n0 = blockIdx.x*G4, t = threadIdx.x;
  #pragma unroll
  for (int g = 0; g < G4; g++) qv[g][t] = q[(n0+g)*D_ + t];
  __syncthreads();
  {
    float acc[G4] = {0.f,0.f,0.f,0.f};
    const float* wrow = Wq + t*D_;
    #pragma unroll 4
    for (int k = 0; k < D_; k += 4){
      float4 w = *(const float4*)(wrow + k);
      #pragma unroll
      for (int g = 0; g < G4; g++)
        acc[g] += qv[g][k]*w.x + qv[g][k+1]*w.y + qv[g][k+2]*w.z + qv[g][k+3]*w.w;
    }
    #pragma unroll
    for (int g = 0; g < G4; g++) qp[g][t] = acc[g];
  }
  __syncthreads();
  float L[G4] = {0.f,0.f,0.f,0.f};
  {
    const float* crow = cb + t*D_;
    #pragma unroll 4
    for (int k = 0; k < D_; k += 4){
      float4 w = *(const float4*)(crow + k);
      #pragma unroll
      for (int g = 0; g < G4; g++)
        L[g] += qp[g][k]*w.x + qp[g][k+1]*w.y + qp[g][k+2]*w.z + qp[g][k+3]*w.w;
    }
  }
  float m[G4], e[G4], s[G4];
  #pragma unroll
  for (int g = 0; g < G4; g++){ L[g] *= INV16; m[g] = wred_max(L[g]); }
  if ((t & 63) == 0)
    #pragma unroll
    for (int g = 0; g < G4; g++) redA[g][t >> 6] = m[g];
  __syncthreads();
  #pragma unroll
  for (int g = 0; g < G4; g++){
    m[g] = fmaxf(fmaxf(redA[g][0], redA[g][1]), fmaxf(redA[g][2], redA[g][3]));
    e[g] = __expf(L[g] - m[g]);
    s[g] = wred_sum(e[g]);
  }
  if ((t & 63) == 0)
    #pragma unroll
    for (int g = 0; g < G4; g++) redB2[g][t >> 6] = s[g];
  __syncthreads();
  #pragma unroll
  for (int g = 0; g < G4; g++){
    float ss = redB2[g][0] + redB2[g][1] + redB2[g][2] + redB2[g][3];
    float w = e[g] / ss;
    cwl[g][t] = w;
    cw_ws[(n0+g)*C_ + t] = w;
  }
  __syncthreads();
  if (t < R_){
    float qd[G4] = {0.f,0.f,0.f,0.f}, md[G4] = {0.f,0.f,0.f,0.f};
    const float* rrow = rcb + t*D_;
    const float* mrow = MT_f32 + t*C_;
    #pragma unroll 4
    for (int k = 0; k < D_; k += 4){
      float4 wv = *(const float4*)(rrow + k);
      float4 mv = *(const float4*)(mrow + k);
      #pragma unroll
      for (int g = 0; g < G4; g++){
        qd[g] += qp[g][k]*wv.x + qp[g][k+1]*wv.y + qp[g][k+2]*wv.z + qp[g][k+3]*wv.w;
        md[g] += cwl[g][k]*mv.x + cwl[g][k+1]*mv.y + cwl[g][k+2]*mv.z + cwl[g][k+3]*mv.w;
      }
    }
    #pragma unroll
    for (int g = 0; g < G4; g++){
      float Lr = (qd[g] - md[g]) * INV16;
      float mr = wred_max(Lr);
      float er = __expf(Lr - mr);
      float sr = wred_sum(er);
      rcw_ws[(n0+g)*R_ + t] = er / sr;
    }
  }
}

// ---------------- K2a: persistent-n, async dbuf K staging (global_load_lds) ---
// block = n (512 thr, 8 waves); 8 tiles x 32 s-rows. K staged fp32 via
// global_load_lds with XOR-permuted per-lane SOURCE (linear LDS dest);
// fragments converted fp32->bf16 at read. Wave w owns c-frags {w, w+8} (both
// sj), r-frag (w&3) on s-frag (w>>2), MT-frag (w&3) for WM.
__global__ __launch_bounds__(512, 2) void k2a(const float* __restrict__ Kt,
    const ushortT* __restrict__ a1pk, const ushortT* __restrict__ mtpk,
    const float* __restrict__ cw_ws, const float* __restrict__ rcw_ws,
    const float* __restrict__ rlogit, float* __restrict__ comb_ws,
    float* __restrict__ out_ew)
{
  __shared__ __align__(16) float  Kbuf[2][32*256];   // 64 KB fp32 dbuf
  __shared__ __align__(16) ushortT Wtile[32*256];    // 16 KB bf16 (swz)
  __shared__ float redS[8][32], redW[8][32];         // c-softmax partials
  __shared__ float red3S[4][32], red3W[4][32];       // r-softmax partials

  int n   = blockIdx.x;
  int tid = threadIdx.x;
  int lane = tid & 63, w = tid >> 6;
  int l15 = lane & 15, l4 = lane >> 4;
  int sjw = w >> 2;          // owned s-frag for R/WM side (0..1)
  int rfw = w & 3;           // owned r-frag / MT-frag (0..3)
  float gate  = 1.f / (1.f + __expf(-rlogit[0]));
  float inv1g = 1.f / (1.f + gate);

  const float* Kn = Kt + (size_t)n*S_*D_;
  const ushortT* a1b = a1pk + (size_t)lane*8;
  const ushortT* mtb = mtpk + (size_t)lane*8;

  // per-block constant weight vectors
  float4 cwv[2];
  #pragma unroll
  for (int f = 0; f < 2; f++)
    cwv[f] = *(const float4*)(cw_ws + n*C_ + (w + 8*f)*16 + l4*4);
  float4 rcwv = *(const float4*)(rcw_ws + n*R_ + rfw*16 + l4*4);

  // ---- prologue: stage tile 0 -> Kbuf[0] (rows w*4..w*4+3) ----
  #pragma unroll
  for (int j = 0; j < 4; j++){
    int r = w*4 + j;
    gload_lds16(Kn + (size_t)r*D_ + ((lane ^ (r & 7)) << 2), &Kbuf[0][r*256]);
  }
  __syncthreads();                                   // B0 (drains stage)

  #pragma unroll
  for (int t = 0; t < 8; t++){
    const float* buf = Kbuf[t & 1];
    // ---- issue async stage of tile t+1 (overlaps this tile's compute) ----
    if (t < 7){
      const float* KnT = Kn + (size_t)(t + 1)*32*D_;
      float* nbuf = Kbuf[(t + 1) & 1];
      #pragma unroll
      for (int j = 0; j < 4; j++){
        int r = w*4 + j;
        gload_lds16(KnT + (size_t)r*D_ + ((lane ^ (r & 7)) << 2), &nbuf[r*256]);
      }
    }

    // ---- GEMM1: accC[2 cf][2 sj] + accR (r-frag rfw, s-frag sjw) ----
    bf8 bnxC[2], bnxR;
    bnxC[0] = *(const bf8*)(a1b + (size_t)(w)*512);
    bnxC[1] = *(const bf8*)(a1b + (size_t)(w + 8)*512);
    bnxR    = *(const bf8*)(a1b + (size_t)(16 + rfw)*512);
    f4 accC[2][2]; f4 accR = (f4)0.f;
    accC[0][0] = (f4)0.f; accC[0][1] = (f4)0.f;
    accC[1][0] = (f4)0.f; accC[1][1] = (f4)0.f;
    #pragma unroll
    for (int ks = 0; ks < 8; ks++){
      bf8 kf0 = kf_read(buf,      l15, ks*8 + l4*2);
      bf8 kf1 = kf_read(buf, 16 + l15, ks*8 + l4*2);
      #pragma unroll
      for (int f = 0; f < 2; f++){
        bf8 aC = bnxC[f];
        if (ks < 7)
          bnxC[f] = *(const bf8*)(a1b + (size_t)((ks+1)*20 + w + 8*f)*512);
        accC[f][0] = __builtin_amdgcn_mfma_f32_16x16x32_bf16(aC, kf0, accC[f][0], 0, 0, 0);
        accC[f][1] = __builtin_amdgcn_mfma_f32_16x16x32_bf16(aC, kf1, accC[f][1], 0, 0, 0);
      }
      bf8 aR = bnxR;
      if (ks < 7)
        bnxR = *(const bf8*)(a1b + (size_t)((ks+1)*20 + 16 + rfw)*512);
      bf8 kfr = sjw ? kf1 : kf0;
      accR = __builtin_amdgcn_mfma_f32_16x16x32_bf16(aR, kfr, accR, 0, 0, 0);
    }

    // ---- softmax-c partials (exp in place, unnormalized) + Wexp write ----
    float se[2] = {0.f, 0.f}, sb[2] = {0.f, 0.f};
    #pragma unroll
    for (int f = 0; f < 2; f++){
      int cbyte = ((w + 8*f)*16 + l4*4) * 2;
      #pragma unroll
      for (int sj = 0; sj < 2; sj++){
        float e0 = __expf(accC[f][sj][0] * INV16);
        float e1 = __expf(accC[f][sj][1] * INV16);
        float e2 = __expf(accC[f][sj][2] * INV16);
        float e3 = __expf(accC[f][sj][3] * INV16);
        se[sj] += (e0 + e1) + (e2 + e3);
        sb[sj] += e0*cwv[f].x + e1*cwv[f].y + e2*cwv[f].z + e3*cwv[f].w;
        int s_ = sj*16 + l15;
        *(uint32*)((char*)Wtile + swz(s_, cbyte))     = packbf(e0, e1);
        *(uint32*)((char*)Wtile + swz(s_, cbyte + 4)) = packbf(e2, e3);
      }
    }
    #pragma unroll
    for (int sj = 0; sj < 2; sj++){
      se[sj] += __shfl_xor(se[sj], 16); se[sj] += __shfl_xor(se[sj], 32);
      sb[sj] += __shfl_xor(sb[sj], 16); sb[sj] += __shfl_xor(sb[sj], 32);
    }
    if (l4 == 0){
      #pragma unroll
      for (int sj = 0; sj < 2; sj++){
        redS[w][sj*16 + l15] = se[sj];
        redW[w][sj*16 + l15] = sb[sj];
      }
    }
    __syncthreads();                                 // B2 (Wexp + partials; stage drained)

    int colr = sjw*16 + l15;
    float rcp_q;
    {
      float sS = 0.f;
      #pragma unroll
      for (int i = 0; i < 8; i++) sS += redS[i][colr];
      rcp_q = 1.f / sS;
    }
    float bwc = 0.f;
    if (w < 2){
      int colb = w*16 + l15;
      float sS = 0.f, sW = 0.f;
      #pragma unroll
      for (int i = 0; i < 8; i++){ sS += redS[i][colb]; sW += redW[i][colb]; }
      bwc = sW / sS;
    }

    // ---- WM: MT-frag rfw x Wexp[s-frag sjw]^T ----
    bf8 mnx = *(const bf8*)(mtb + (size_t)(rfw)*512);
    f4 wm = (f4)0.f;
    #pragma unroll
    for (int ks = 0; ks < 8; ks++){
      bf8 wb = *(const bf8*)((const char*)Wtile + swz(sjw*16 + l15, ks*64 + l4*16));
      bf8 a = mnx;
      if (ks < 7) mnx = *(const bf8*)(mtb + (size_t)((ks+1)*4 + rfw)*512);
      wm = __builtin_amdgcn_mfma_f32_16x16x32_bf16(a, wb, wm, 0, 0, 0);
    }

    // ---- r-softmax partials ----
    float se3, sc3;
    {
      float e0 = __expf((accR[0] - wm[0]*rcp_q) * INV16);
      float e1 = __expf((accR[1] - wm[1]*rcp_q) * INV16);
      float e2 = __expf((accR[2] - wm[2]*rcp_q) * INV16);
      float e3 = __expf((accR[3] - wm[3]*rcp_q) * INV16);
      se3 = (e0 + e1) + (e2 + e3);
      sc3 = e0*rcwv.x + e1*rcwv.y + e2*rcwv.z + e3*rcwv.w;
    }
    se3 += __shfl_xor(se3, 16); se3 += __shfl_xor(se3, 32);
    sc3 += __shfl_xor(sc3, 16); sc3 += __shfl_xor(sc3, 32);
    if (l4 == 0){
      red3S[rfw][colr] = se3;
      red3W[rfw][colr] = sc3;
    }
    __syncthreads();                                 // B3 (publishes red3; frees buffers)

    // ---- combine + comb write (waves 0,1 own cols w*16+l15) ----
    if (w < 2){
      int col = w*16 + l15;
      float sS3 = red3S[0][col] + red3S[1][col] + red3S[2][col] + red3S[3][col];
      float sW3 = red3W[0][col] + red3W[1][col] + red3W[2][col] + red3W[3][col];
      float comb = bwc + gate * (sW3 / sS3);
      if (l4 == 0){
        int sabs = n*S_ + t*32 + col;
        out_ew[sabs]  = comb * inv1g;
        comb_ws[sabs] = comb;
      }
    }
  }
}

// ---------------- K2b: summary streaming pass (HBM-bound) ---------------------
__global__ __launch_bounds__(256) void k2b(const float* __restrict__ Vt,
    const float* __restrict__ comb_ws, float* __restrict__ sum_ws)
{
  __shared__ float cl[S_];
  __shared__ float4 part[4][64];
  int n = blockIdx.x, tid = threadIdx.x;
  int lane = tid & 63, w = tid >> 6;
  cl[tid] = comb_ws[n*S_ + tid];
  __syncthreads();
  const float* Vn = Vt + (size_t)n*S_*D_ + (size_t)(w*64)*D_ + lane*4;
  float4 a0 = {0,0,0,0}, a1 = {0,0,0,0};
  #pragma unroll 8
  for (int j = 0; j < 64; j += 2){
    float4 v0 = *(const float4*)(Vn + (size_t)j*D_);
    float4 v1 = *(const float4*)(Vn + (size_t)(j+1)*D_);
    float c0 = cl[w*64 + j], c1 = cl[w*64 + j + 1];
    a0.x = fmaf(c0, v0.x, a0.x); a0.y = fmaf(c0, v0.y, a0.y);
    a0.z = fmaf(c0, v0.z, a0.z); a0.w = fmaf(c0, v0.w, a0.w);
    a1.x = fmaf(c1, v1.x, a1.x); a1.y = fmaf(c1, v1.y, a1.y);
    a1.z = fmaf(c1, v1.z, a1.z); a1.w = fmaf(c1, v1.w, a1.w);
  }
  float4 acc = {a0.x+a1.x, a0.y+a1.y, a0.z+a1.z, a0.w+a1.w};
  part[w][lane] = acc;
  __syncthreads();
  if (tid < 64){
    float4 p0 = part[0][tid], p1 = part[1][tid], p2 = part[2][tid], p3 = part[3][tid];
    float4 r = {p0.x+p1.x+p2.x+p3.x, p0.y+p1.y+p2.y+p3.y,
                p0.z+p1.z+p2.z+p3.z, p0.w+p1.w+p2.w+p3.w};
    *(float4*)(sum_ws + (size_t)n*D_ + tid*4) = r;
  }
}

// ---------------- K3: readout GEMM (MFMA, bf16) --------------------------------
__global__ __launch_bounds__(256) void k3(const float* __restrict__ sum_ws,
    const ushortT* __restrict__ Wcr_bf, const float* __restrict__ bc,
    const float* __restrict__ br, float* __restrict__ out)
{
  __shared__ __align__(16) ushortT Stile[64*256];
  int bx = blockIdx.x;
  int ot = bx >> 4;
  int nt = bx & 15;
  int tid = threadIdx.x;
  int lane = tid & 63, wid = tid >> 6;
  int l15 = lane & 15, l4 = lane >> 4;

  const float* Sp = sum_ws + (size_t)nt*64*D_;
  #pragma unroll
  for (int j = 0; j < 8; j++){
    int ch = tid + j*256;
    int row = ch >> 5, blk = ch & 31;
    const float* src = Sp + row*D_ + blk*8;
    float4 a = *(const float4*)src;
    float4 b = *(const float4*)(src + 4);
    uint4 wv = {packbf(a.x,a.y), packbf(a.z,a.w), packbf(b.x,b.y), packbf(b.z,b.w)};
    *(uint4*)((char*)Stile + swz(row, blk*16)) = wv;
  }
  __syncthreads();

  int o0 = ot*64 + wid*16;
  const ushortT* Ap = Wcr_bf + (size_t)(o0 + l15)*D_ + l4*8;
  f4 acc[4];
  #pragma unroll
  for (int j = 0; j < 4; j++) acc[j] = (f4)0.f;
  #pragma unroll
  for (int k = 0; k < 8; k++){
    bf8 a = *(const bf8*)(Ap + k*32);
    #pragma unroll
    for (int nj = 0; nj < 4; nj++){
      bf8 b = *(const bf8*)((const char*)Stile + swz(nj*16 + l15, k*64 + l4*16));
      acc[nj] = __builtin_amdgcn_mfma_f32_16x16x32_bf16(a, b, acc[nj], 0, 0, 0);
    }
  }
  int obase = o0 + l4*4;
  if (obase < 1256){
    float4 bias;
    if (obase < CLS_) bias = *(const float4*)(bc + obase);
    else              bias = *(const float4*)(br + (obase - CLS_));
    #pragma unroll
    for (int nj = 0; nj < 4; nj++){
      int nn = nt*64 + nj*16 + l15;
      float4 v = {acc[nj][0]+bias.x, acc[nj][1]+bias.y, acc[nj][2]+bias.z, acc[nj][3]+bias.w};
      if (obase < CLS_) *(float4*)(out + (size_t)nn*CLS_ + obase) = v;
      else              *(float4*)(out + (size_t)N_*CLS_ + (size_t)nn*D_ + (obase - CLS_)) = v;
    }
  }
}

extern "C" void kernel_launch(void* const* d_in, const int* in_sizes, int n_in,
                              void* d_out, int out_size, void* d_ws, size_t ws_size,
                              hipStream_t stream)
{
  const float* q    = (const float*)d_in[0];
  const float* Kt   = (const float*)d_in[1];
  const float* Vt   = (const float*)d_in[2];
  const float* cb   = (const float*)d_in[3];
  const float* rcb  = (const float*)d_in[4];
  const float* Wq   = (const float*)d_in[5];
  const float* rlg  = (const float*)d_in[6];
  const float* Wc   = (const float*)d_in[7];
  const float* bc   = (const float*)d_in[8];
  const float* Wr   = (const float*)d_in[9];
  const float* br   = (const float*)d_in[10];
  float* out = (float*)d_out;
  float* ws  = (float*)d_ws;

  float* cw_ws   = ws;                          // N*C
  float* rcw_ws  = ws + 262144;                 // N*R
  float* sum_ws  = ws + 327680;                 // N*D
  float* comb_ws = ws + 589824;                 // N*S
  float* MT_f32  = ws + 851968;                 // R*C
  ushortT* a1pk   = (ushortT*)(ws + 868352);    // 320*D frag-packed
  ushortT* mtpk   = a1pk + (C_ + R_)*D_;        // R*C frag-packed
  ushortT* Wcr_bf = mtpk + R_*C_;               // 1280*D (Wc ; Wr ; zero pad)

  float* out_logits = out;
  float* out_ew     = out + (size_t)N_*CLS_ + (size_t)N_*D_;

  k0 <<<128,   256, 0, stream>>>(cb, rcb, Wc, Wr, a1pk, Wcr_bf, MT_f32, mtpk);
  k1 <<<N_/G4, 256, 0, stream>>>(q, cb, rcb, Wq, MT_f32, cw_ws, rcw_ws);
  k2a<<<N_,    512, 0, stream>>>(Kt, a1pk, mtpk, cw_ws, rcw_ws, rlg, comb_ws, out_ew);
  k2b<<<N_,    256, 0, stream>>>(Vt, comb_ws, sum_ws);
  k3 <<<320,   256, 0, stream>>>(sum_ws, Wcr_bf, bc, br, out_logits);
}

// Round 17
// 247.840 us; speedup vs baseline: 1.1459x; 1.1459x over previous
//
#include <hip/hip_runtime.h>
#include <hip/hip_bf16.h>
#include <math.h>

#define N_   1024
#define S_   256
#define D_   256
#define C_   256
#define R_   64
#define CLS_ 1000
#define INV16 0.0625f

typedef unsigned short ushortT;
typedef unsigned int uint32;
typedef short bf8 __attribute__((ext_vector_type(8)));
typedef float f4 __attribute__((ext_vector_type(4)));

static __device__ __forceinline__ float bf2f(uint32 u){
  return __uint_as_float(u << 16);
}
static __device__ __forceinline__ ushortT f2bf(float f){
  uint32 x = __float_as_uint(f);
  uint32 r = x + 0x7FFFu + ((x >> 16) & 1u);
  return (ushortT)(r >> 16);
}
static __device__ __forceinline__ uint32 packbf(float a, float b){
  return ((uint32)f2bf(b) << 16) | (uint32)f2bf(a);
}
static __device__ __forceinline__ float wred_max(float v){
  for (int o = 32; o; o >>= 1) v = fmaxf(v, __shfl_xor(v, o));
  return v;
}
static __device__ __forceinline__ float wred_sum(float v){
  for (int o = 32; o; o >>= 1) v += __shfl_xor(v, o);
  return v;
}
// swizzled byte offset inside a [rows][256]-bf16 LDS tile (row stride 512B)
static __device__ __forceinline__ int swz(int row, int colbyte){
  return row*512 + ((colbyte & ~15) ^ ((row & 7) << 4)) + (colbyte & 15);
}
// fragment-ready packed index for a [rows x 256] matrix, 16-row frags, K-step 32
static __device__ __forceinline__ int pkidx(int row, int col, int nfrag){
  int ks = col >> 5, hi = (col >> 3) & 3, e = col & 7;
  int frag = row >> 4, l15p = row & 15;
  return ((ks*nfrag + frag)*64 + hi*16 + l15p)*8 + e;
}

// ---------------- K0: weight prep + MT = cb @ rcb^T + sum_ws zero -------------
__global__ __launch_bounds__(256) void k0(const float* __restrict__ cb,
    const float* __restrict__ rcb, const float* __restrict__ Wc,
    const float* __restrict__ Wr, ushortT* __restrict__ a1pk,
    ushortT* __restrict__ Wcr_bf, float* __restrict__ MT_f32,
    ushortT* __restrict__ mtpk, float* __restrict__ sum_ws)
{
  __shared__ float rl[D_];
  int bid = blockIdx.x, t = threadIdx.x;
  int gtid = bid*256 + t;
  int stride = gridDim.x*256;
  for (int e = gtid; e < (C_ + R_)*D_; e += stride){
    int row = e >> 8, col = e & 255;
    float v = (row < C_) ? cb[e] : rcb[e - C_*D_];
    a1pk[pkidx(row, col, 20)] = f2bf(v);
  }
  for (int e = gtid; e < CLS_*D_; e += stride) Wcr_bf[e] = f2bf(Wc[e]);
  for (int e = gtid; e < D_*D_; e += stride)  Wcr_bf[CLS_*D_ + e] = f2bf(Wr[e]);
  for (int e = gtid; e < 24*D_; e += stride)  Wcr_bf[1256*D_ + e] = 0;
  for (int e = gtid; e < N_*D_; e += stride)  sum_ws[e] = 0.f;

  if (bid < R_){
    rl[t] = rcb[bid*D_ + t];
    __syncthreads();
    float acc = 0.f;
    const float* crow = cb + t*D_;
    #pragma unroll 8
    for (int k = 0; k < D_; k += 4){
      float4 w = *(const float4*)(crow + k);
      acc += w.x*rl[k] + w.y*rl[k+1] + w.z*rl[k+2] + w.w*rl[k+3];
    }
    MT_f32[bid*C_ + t] = acc;
    mtpk[pkidx(bid, t, 4)] = f2bf(acc);
  }
}

// ---------------- K1: per-query pass, batched x4 ------------------------------
#define G4 4
__global__ __launch_bounds__(256) void k1(const float* __restrict__ q,
    const float* __restrict__ cb, const float* __restrict__ rcb,
    const float* __restrict__ Wq, const float* __restrict__ MT_f32,
    float* __restrict__ cw_ws, float* __restrict__ rcw_ws)
{
  __shared__ float qv[G4][D_], qp[G4][D_], cwl[G4][C_];
  __shared__ float redA[G4][4], redB2[G4][4];
  int n0 = blockIdx.x*G4, t = threadIdx.x;
  #pragma unroll
  for (int g = 0; g < G4; g++) qv[g][t] = q[(n0+g)*D_ + t];
  __syncthreads();
  {
    float acc[G4] = {0.f,0.f,0.f,0.f};
    const float* wrow = Wq + t*D_;
    #pragma unroll 4
    for (int k = 0; k < D_; k += 4){
      float4 w = *(const float4*)(wrow + k);
      #pragma unroll
      for (int g = 0; g < G4; g++)
        acc[g] += qv[g][k]*w.x + qv[g][k+1]*w.y + qv[g][k+2]*w.z + qv[g][k+3]*w.w;
    }
    #pragma unroll
    for (int g = 0; g < G4; g++) qp[g][t] = acc[g];
  }
  __syncthreads();
  float L[G4] = {0.f,0.f,0.f,0.f};
  {
    const float* crow = cb + t*D_;
    #pragma unroll 4
    for (int k = 0; k < D_; k += 4){
      float4 w = *(const float4*)(crow + k);
      #pragma unroll
      for (int g = 0; g < G4; g++)
        L[g] += qp[g][k]*w.x + qp[g][k+1]*w.y + qp[g][k+2]*w.z + qp[g][k+3]*w.w;
    }
  }
  float m[G4], e[G4], s[G4];
  #pragma unroll
  for (int g = 0; g < G4; g++){ L[g] *= INV16; m[g] = wred_max(L[g]); }
  if ((t & 63) == 0)
    #pragma unroll
    for (int g = 0; g < G4; g++) redA[g][t >> 6] = m[g];
  __syncthreads();
  #pragma unroll
  for (int g = 0; g < G4; g++){
    m[g] = fmaxf(fmaxf(redA[g][0], redA[g][1]), fmaxf(redA[g][2], redA[g][3]));
    e[g] = __expf(L[g] - m[g]);
    s[g] = wred_sum(e[g]);
  }
  if ((t & 63) == 0)
    #pragma unroll
    for (int g = 0; g < G4; g++) redB2[g][t >> 6] = s[g];
  __syncthreads();
  #pragma unroll
  for (int g = 0; g < G4; g++){
    float ss = redB2[g][0] + redB2[g][1] + redB2[g][2] + redB2[g][3];
    float w = e[g] / ss;
    cwl[g][t] = w;
    cw_ws[(n0+g)*C_ + t] = w;
  }
  __syncthreads();
  if (t < R_){
    float qd[G4] = {0.f,0.f,0.f,0.f}, md[G4] = {0.f,0.f,0.f,0.f};
    const float* rrow = rcb + t*D_;
    const float* mrow = MT_f32 + t*C_;
    #pragma unroll 4
    for (int k = 0; k < D_; k += 4){
      float4 wv = *(const float4*)(rrow + k);
      float4 mv = *(const float4*)(mrow + k);
      #pragma unroll
      for (int g = 0; g < G4; g++){
        qd[g] += qp[g][k]*wv.x + qp[g][k+1]*wv.y + qp[g][k+2]*wv.z + qp[g][k+3]*wv.w;
        md[g] += cwl[g][k]*mv.x + cwl[g][k+1]*mv.y + cwl[g][k+2]*mv.z + cwl[g][k+3]*mv.w;
      }
    }
    #pragma unroll
    for (int g = 0; g < G4; g++){
      float Lr = (qd[g] - md[g]) * INV16;
      float mr = wred_max(Lr);
      float er = __expf(Lr - mr);
      float sr = wred_sum(er);
      rcw_ws[(n0+g)*R_ + t] = er / sr;
    }
  }
}

// ---------------- K2a: weights + fused V summary, 32-s tile, 4 blocks/CU ------
// block = (n, 32-s tile); 4 waves. Wave w owns: c-frags {w+4f} on both s-frags;
// r-frags {2*(w>>1), +1} on s-frag (w&1); matching MT frags for WM.
// After comb, wave w streams V rows [w*8, +8) and atomically accumulates.
__global__ __launch_bounds__(256, 4) void k2a(const float* __restrict__ Kt,
    const float* __restrict__ Vt, const ushortT* __restrict__ a1pk,
    const ushortT* __restrict__ mtpk, const float* __restrict__ cw_ws,
    const float* __restrict__ rcw_ws, const float* __restrict__ rlogit,
    float* __restrict__ sum_ws, float* __restrict__ out_ew)
{
  __shared__ __align__(16) ushortT Ktile[32*256];   // 16 KB
  __shared__ __align__(16) ushortT Wtile[32*256];   // 16 KB
  __shared__ float redS[4][32], redW[4][32];        // 1 KB (c-softmax)
  __shared__ float red3S[4][32], red3W[4][32];      // 1 KB (r-softmax)
  __shared__ float combl[32];

  int bx  = blockIdx.x;
  int n   = bx >> 3;
  int s0  = (bx & 7) * 32;
  int tid = threadIdx.x;
  int lane = tid & 63, w = tid >> 6;
  int l15 = lane & 15, l4 = lane >> 4;
  int rp  = w >> 1;          // r-frag pair index (0..1)
  int sjr = w & 1;           // owned s-frag for R-side
  float gate  = 1.f / (1.f + __expf(-rlogit[0]));
  float inv1g = 1.f / (1.f + gate);

  const float* Kn = Kt + (size_t)n*S_*D_ + (size_t)s0*D_;

  // ---- stage K tile (32x256) fp32 -> bf16 swz LDS ----
  #pragma unroll
  for (int j = 0; j < 4; j++){
    int ch = tid + j*256;
    int row = ch >> 5, blk = ch & 31;
    const float* src = Kn + row*D_ + blk*8;
    float4 a = *(const float4*)src;
    float4 b = *(const float4*)(src + 4);
    uint4 wv = {packbf(a.x,a.y), packbf(a.z,a.w), packbf(b.x,b.y), packbf(b.z,b.w)};
    *(uint4*)((char*)Ktile + swz(row, blk*16)) = wv;
  }
  __syncthreads();                                   // B1

  // ---- GEMM1: accC[4 cf][2 sj] + accR[2 rf] (s-frag sjr) --------------------
  const ushortT* a1b = a1pk + (size_t)lane*8;
  bf8 bnxC[4], bnxR[2];
  #pragma unroll
  for (int f = 0; f < 4; f++)
    bnxC[f] = *(const bf8*)(a1b + (size_t)((w + 4*f)*64)*8);
  #pragma unroll
  for (int i = 0; i < 2; i++)
    bnxR[i] = *(const bf8*)(a1b + (size_t)((16 + 2*rp + i)*64)*8);
  f4 accC[4][2]; f4 accR[2];
  accR[0] = (f4)0.f; accR[1] = (f4)0.f;
  #pragma unroll
  for (int f = 0; f < 4; f++){ accC[f][0] = (f4)0.f; accC[f][1] = (f4)0.f; }
  #pragma unroll
  for (int ks = 0; ks < 8; ks++){
    bf8 kf0 = *(const bf8*)((const char*)Ktile + swz(     l15, ks*64 + l4*16));
    bf8 kf1 = *(const bf8*)((const char*)Ktile + swz(16 + l15, ks*64 + l4*16));
    bf8 kfr = sjr ? kf1 : kf0;
    #pragma unroll
    for (int f = 0; f < 4; f++){
      bf8 aC = bnxC[f];
      if (ks < 7)
        bnxC[f] = *(const bf8*)(a1b + (size_t)(((ks+1)*20 + w + 4*f)*64)*8);
      accC[f][0] = __builtin_amdgcn_mfma_f32_16x16x32_bf16(aC, kf0, accC[f][0], 0, 0, 0);
      accC[f][1] = __builtin_amdgcn_mfma_f32_16x16x32_bf16(aC, kf1, accC[f][1], 0, 0, 0);
    }
    #pragma unroll
    for (int i = 0; i < 2; i++){
      bf8 aR = bnxR[i];
      if (ks < 7)
        bnxR[i] = *(const bf8*)(a1b + (size_t)(((ks+1)*20 + 16 + 2*rp + i)*64)*8);
      accR[i] = __builtin_amdgcn_mfma_f32_16x16x32_bf16(aR, kfr, accR[i], 0, 0, 0);
    }
  }

  // ---- preload WM's first MT frags (hidden under exp phase) -----------------
  const ushortT* mtb = mtpk + (size_t)lane*8;
  bf8 mnx[2];
  #pragma unroll
  for (int i = 0; i < 2; i++)
    mnx[i] = *(const bf8*)(mtb + (size_t)((2*rp + i)*64)*8);

  // ---- softmax-c partials (exp in place, unnormalized) + Wexp write ---------
  float4 cwv[4];
  #pragma unroll
  for (int f = 0; f < 4; f++)
    cwv[f] = *(const float4*)(cw_ws + n*C_ + (w + 4*f)*16 + l4*4);
  float se[2] = {0,0}, sb[2] = {0,0};
  #pragma unroll
  for (int f = 0; f < 4; f++){
    int cbyte = ((w + 4*f)*16 + l4*4) * 2;
    #pragma unroll
    for (int sj = 0; sj < 2; sj++){
      float e0 = __expf(accC[f][sj][0] * INV16);
      float e1 = __expf(accC[f][sj][1] * INV16);
      float e2 = __expf(accC[f][sj][2] * INV16);
      float e3 = __expf(accC[f][sj][3] * INV16);
      se[sj] += (e0 + e1) + (e2 + e3);
      sb[sj] += e0*cwv[f].x + e1*cwv[f].y + e2*cwv[f].z + e3*cwv[f].w;
      int s_ = sj*16 + l15;
      *(uint32*)((char*)Wtile + swz(s_, cbyte))     = packbf(e0, e1);
      *(uint32*)((char*)Wtile + swz(s_, cbyte + 4)) = packbf(e2, e3);
    }
  }
  #pragma unroll
  for (int sj = 0; sj < 2; sj++){
    se[sj] += __shfl_xor(se[sj], 16); se[sj] += __shfl_xor(se[sj], 32);
    sb[sj] += __shfl_xor(sb[sj], 16); sb[sj] += __shfl_xor(sb[sj], 32);
  }
  if (l4 == 0){
    #pragma unroll
    for (int sj = 0; sj < 2; sj++){
      redS[w][sj*16 + l15] = se[sj];
      redW[w][sj*16 + l15] = sb[sj];
    }
  }
  __syncthreads();                                   // B2 (publishes Wexp + partials)

  float bw_q, rcp_q;
  {
    int sq = sjr*16 + l15;     // for writer waves (w<2) this is the owned col
    float sS = redS[0][sq] + redS[1][sq] + redS[2][sq] + redS[3][sq];
    float sW = redW[0][sq] + redW[1][sq] + redW[2][sq] + redW[3][sq];
    rcp_q = 1.f / sS;
    bw_q  = sW * rcp_q;
  }

  // ---- WM: MT frags {2rp,2rp+1} x Wexp[s-frag sjr]^T; depth-1 from L2 -------
  f4 wm[2]; wm[0] = (f4)0.f; wm[1] = (f4)0.f;
  #pragma unroll
  for (int ks = 0; ks < 8; ks++){
    bf8 wb = *(const bf8*)((const char*)Wtile + swz(sjr*16 + l15, ks*64 + l4*16));
    #pragma unroll
    for (int i = 0; i < 2; i++){
      bf8 a = mnx[i];
      if (ks < 7)
        mnx[i] = *(const bf8*)(mtb + (size_t)(((ks+1)*4 + 2*rp + i)*64)*8);
      wm[i] = __builtin_amdgcn_mfma_f32_16x16x32_bf16(a, wb, wm[i], 0, 0, 0);
    }
  }

  // ---- r-softmax partials: l3 = (accR - wm*rcp_q)/16 ------------------------
  float se3 = 0.f, sc3 = 0.f;
  #pragma unroll
  for (int i = 0; i < 2; i++){
    float4 rv = *(const float4*)(rcw_ws + n*R_ + (2*rp + i)*16 + l4*4);
    float e0 = __expf((accR[i][0] - wm[i][0]*rcp_q) * INV16);
    float e1 = __expf((accR[i][1] - wm[i][1]*rcp_q) * INV16);
    float e2 = __expf((accR[i][2] - wm[i][2]*rcp_q) * INV16);
    float e3 = __expf((accR[i][3] - wm[i][3]*rcp_q) * INV16);
    se3 += (e0 + e1) + (e2 + e3);
    sc3 += e0*rv.x + e1*rv.y + e2*rv.z + e3*rv.w;
  }
  se3 += __shfl_xor(se3, 16); se3 += __shfl_xor(se3, 32);
  sc3 += __shfl_xor(sc3, 16); sc3 += __shfl_xor(sc3, 32);
  if (l4 == 0){
    red3S[w][sjr*16 + l15] = se3;
    red3W[w][sjr*16 + l15] = sc3;
  }
  __syncthreads();                                   // B3

  // ---- combine r-halves + comb write (waves 0,1 own cols w*16+l15) ----------
  if (w < 2){
    int sq = w*16 + l15;
    float sS3 = red3S[w][sq] + red3S[w + 2][sq];
    float sW3 = red3W[w][sq] + red3W[w + 2][sq];
    float comb = bw_q + gate * (sW3 / sS3);
    if (l4 == 0){
      int sabs = n*S_ + s0 + sq;
      out_ew[sabs] = comb * inv1g;
      combl[sq]    = comb;
    }
  }
  __syncthreads();                                   // B4 (combl ready)

  // ---- fused V summary: wave w streams rows [w*8, +8); lane covers 4 d ------
  {
    const float* vp = Vt + (size_t)n*S_*D_ + (size_t)(s0 + w*8)*D_ + lane*4;
    float4 sacc = {0.f, 0.f, 0.f, 0.f};
    #pragma unroll
    for (int j = 0; j < 8; j++){
      float c = combl[w*8 + j];
      float4 v = *(const float4*)(vp + (size_t)j*D_);
      sacc.x = fmaf(c, v.x, sacc.x); sacc.y = fmaf(c, v.y, sacc.y);
      sacc.z = fmaf(c, v.z, sacc.z); sacc.w = fmaf(c, v.w, sacc.w);
    }
    float* dst = sum_ws + (size_t)n*D_ + lane*4;
    atomicAdd(dst + 0, sacc.x);
    atomicAdd(dst + 1, sacc.y);
    atomicAdd(dst + 2, sacc.z);
    atomicAdd(dst + 3, sacc.w);
  }
}

// ---------------- K3: readout GEMM (MFMA, bf16) --------------------------------
__global__ __launch_bounds__(256) void k3(const float* __restrict__ sum_ws,
    const ushortT* __restrict__ Wcr_bf, const float* __restrict__ bc,
    const float* __restrict__ br, float* __restrict__ out)
{
  __shared__ __align__(16) ushortT Stile[64*256];
  int bx = blockIdx.x;
  int ot = bx >> 4;
  int nt = bx & 15;
  int tid = threadIdx.x;
  int lane = tid & 63, wid = tid >> 6;
  int l15 = lane & 15, l4 = lane >> 4;

  const float* Sp = sum_ws + (size_t)nt*64*D_;
  #pragma unroll
  for (int j = 0; j < 8; j++){
    int ch = tid + j*256;
    int row = ch >> 5, blk = ch & 31;
    const float* src = Sp + row*D_ + blk*8;
    float4 a = *(const float4*)src;
    float4 b = *(const float4*)(src + 4);
    uint4 wv = {packbf(a.x,a.y), packbf(a.z,a.w), packbf(b.x,b.y), packbf(b.z,b.w)};
    *(uint4*)((char*)Stile + swz(row, blk*16)) = wv;
  }
  __syncthreads();

  int o0 = ot*64 + wid*16;
  const ushortT* Ap = Wcr_bf + (size_t)(o0 + l15)*D_ + l4*8;
  f4 acc[4];
  #pragma unroll
  for (int j = 0; j < 4; j++) acc[j] = (f4)0.f;
  #pragma unroll
  for (int k = 0; k < 8; k++){
    bf8 a = *(const bf8*)(Ap + k*32);
    #pragma unroll
    for (int nj = 0; nj < 4; nj++){
      bf8 b = *(const bf8*)((const char*)Stile + swz(nj*16 + l15, k*64 + l4*16));
      acc[nj] = __builtin_amdgcn_mfma_f32_16x16x32_bf16(a, b, acc[nj], 0, 0, 0);
    }
  }
  int obase = o0 + l4*4;
  if (obase < 1256){
    float4 bias;
    if (obase < CLS_) bias = *(const float4*)(bc + obase);
    else              bias = *(const float4*)(br + (obase - CLS_));
    #pragma unroll
    for (int nj = 0; nj < 4; nj++){
      int nn = nt*64 + nj*16 + l15;
      float4 v = {acc[nj][0]+bias.x, acc[nj][1]+bias.y, acc[nj][2]+bias.z, acc[nj][3]+bias.w};
      if (obase < CLS_) *(float4*)(out + (size_t)nn*CLS_ + obase) = v;
      else              *(float4*)(out + (size_t)N_*CLS_ + (size_t)nn*D_ + (obase - CLS_)) = v;
    }
  }
}

extern "C" void kernel_launch(void* const* d_in, const int* in_sizes, int n_in,
                              void* d_out, int out_size, void* d_ws, size_t ws_size,
                              hipStream_t stream)
{
  const float* q    = (const float*)d_in[0];
  const float* Kt   = (const float*)d_in[1];
  const float* Vt   = (const float*)d_in[2];
  const float* cb   = (const float*)d_in[3];
  const float* rcb  = (const float*)d_in[4];
  const float* Wq   = (const float*)d_in[5];
  const float* rlg  = (const float*)d_in[6];
  const float* Wc   = (const float*)d_in[7];
  const float* bc   = (const float*)d_in[8];
  const float* Wr   = (const float*)d_in[9];
  const float* br   = (const float*)d_in[10];
  float* out = (float*)d_out;
  float* ws  = (float*)d_ws;

  float* cw_ws   = ws;                          // N*C
  float* rcw_ws  = ws + 262144;                 // N*R
  float* sum_ws  = ws + 327680;                 // N*D
  float* MT_f32  = ws + 851968;                 // R*C
  ushortT* a1pk   = (ushortT*)(ws + 868352);    // 320*D frag-packed
  ushortT* mtpk   = a1pk + (C_ + R_)*D_;        // R*C frag-packed
  ushortT* Wcr_bf = mtpk + R_*C_;               // 1280*D (Wc ; Wr ; zero pad)

  float* out_logits = out;
  float* out_ew     = out + (size_t)N_*CLS_ + (size_t)N_*D_;

  k0 <<<128,   256, 0, stream>>>(cb, rcb, Wc, Wr, a1pk, Wcr_bf, MT_f32, mtpk, sum_ws);
  k1 <<<N_/G4, 256, 0, stream>>>(q, cb, rcb, Wq, MT_f32, cw_ws, rcw_ws);
  k2a<<<N_*8,  256, 0, stream>>>(Kt, Vt, a1pk, mtpk, cw_ws, rcw_ws, rlg, sum_ws, out_ew);
  k3 <<<320,   256, 0, stream>>>(sum_ws, Wcr_bf, bc, br, out_logits);
}

// Round 18
// 225.387 us; speedup vs baseline: 1.2600x; 1.0996x over previous
//
#include <hip/hip_runtime.h>
#include <hip/hip_bf16.h>
#include <math.h>

#define N_   1024
#define S_   256
#define D_   256
#define C_   256
#define R_   64
#define CLS_ 1000
#define INV16 0.0625f

typedef unsigned short ushortT;
typedef unsigned int uint32;
typedef short bf8 __attribute__((ext_vector_type(8)));
typedef float f4 __attribute__((ext_vector_type(4)));

static __device__ __forceinline__ float bf2f(uint32 u){
  return __uint_as_float(u << 16);
}
static __device__ __forceinline__ ushortT f2bf(float f){
  uint32 x = __float_as_uint(f);
  uint32 r = x + 0x7FFFu + ((x >> 16) & 1u);
  return (ushortT)(r >> 16);
}
static __device__ __forceinline__ uint32 packbf(float a, float b){
  return ((uint32)f2bf(b) << 16) | (uint32)f2bf(a);
}
static __device__ __forceinline__ float wred_max(float v){
  for (int o = 32; o; o >>= 1) v = fmaxf(v, __shfl_xor(v, o));
  return v;
}
static __device__ __forceinline__ float wred_sum(float v){
  for (int o = 32; o; o >>= 1) v += __shfl_xor(v, o);
  return v;
}
// swizzled byte offset inside a [rows][256]-bf16 LDS tile (row stride 512B)
static __device__ __forceinline__ int swz(int row, int colbyte){
  return row*512 + ((colbyte & ~15) ^ ((row & 7) << 4)) + (colbyte & 15);
}
// fragment-ready packed index for a [rows x 256] matrix, 16-row frags, K-step 32
static __device__ __forceinline__ int pkidx(int row, int col, int nfrag){
  int ks = col >> 5, hi = (col >> 3) & 3, e = col & 7;
  int frag = row >> 4, l15p = row & 15;
  return ((ks*nfrag + frag)*64 + hi*16 + l15p)*8 + e;
}

// ---------------- K0: weight prep + MT = cb @ rcb^T ---------------------------
__global__ __launch_bounds__(256) void k0(const float* __restrict__ cb,
    const float* __restrict__ rcb, const float* __restrict__ Wc,
    const float* __restrict__ Wr, ushortT* __restrict__ a1pk,
    ushortT* __restrict__ Wcr_bf, float* __restrict__ MT_f32,
    ushortT* __restrict__ mtpk)
{
  __shared__ float rl[D_];
  int bid = blockIdx.x, t = threadIdx.x;
  int gtid = bid*256 + t;
  int stride = gridDim.x*256;
  for (int e = gtid; e < (C_ + R_)*D_; e += stride){
    int row = e >> 8, col = e & 255;
    float v = (row < C_) ? cb[e] : rcb[e - C_*D_];
    a1pk[pkidx(row, col, 20)] = f2bf(v);
  }
  for (int e = gtid; e < CLS_*D_; e += stride) Wcr_bf[e] = f2bf(Wc[e]);
  for (int e = gtid; e < D_*D_; e += stride)  Wcr_bf[CLS_*D_ + e] = f2bf(Wr[e]);
  for (int e = gtid; e < 24*D_; e += stride)  Wcr_bf[1256*D_ + e] = 0;

  if (bid < R_){
    rl[t] = rcb[bid*D_ + t];
    __syncthreads();
    float acc = 0.f;
    const float* crow = cb + t*D_;
    #pragma unroll 8
    for (int k = 0; k < D_; k += 4){
      float4 w = *(const float4*)(crow + k);
      acc += w.x*rl[k] + w.y*rl[k+1] + w.z*rl[k+2] + w.w*rl[k+3];
    }
    MT_f32[bid*C_ + t] = acc;
    mtpk[pkidx(bid, t, 4)] = f2bf(acc);
  }
}

// ---------------- K1: per-query pass, batched x4 ------------------------------
#define G4 4
__global__ __launch_bounds__(256) void k1(const float* __restrict__ q,
    const float* __restrict__ cb, const float* __restrict__ rcb,
    const float* __restrict__ Wq, const float* __restrict__ MT_f32,
    float* __restrict__ cw_ws, float* __restrict__ rcw_ws)
{
  __shared__ float qv[G4][D_], qp[G4][D_], cwl[G4][C_];
  __shared__ float redA[G4][4], redB2[G4][4];
  int n0 = blockIdx.x*G4, t = threadIdx.x;
  #pragma unroll
  for (int g = 0; g < G4; g++) qv[g][t] = q[(n0+g)*D_ + t];
  __syncthreads();
  {
    float acc[G4] = {0.f,0.f,0.f,0.f};
    const float* wrow = Wq + t*D_;
    #pragma unroll 4
    for (int k = 0; k < D_; k += 4){
      float4 w = *(const float4*)(wrow + k);
      #pragma unroll
      for (int g = 0; g < G4; g++)
        acc[g] += qv[g][k]*w.x + qv[g][k+1]*w.y + qv[g][k+2]*w.z + qv[g][k+3]*w.w;
    }
    #pragma unroll
    for (int g = 0; g < G4; g++) qp[g][t] = acc[g];
  }
  __syncthreads();
  float L[G4] = {0.f,0.f,0.f,0.f};
  {
    const float* crow = cb + t*D_;
    #pragma unroll 4
    for (int k = 0; k < D_; k += 4){
      float4 w = *(const float4*)(crow + k);
      #pragma unroll
      for (int g = 0; g < G4; g++)
        L[g] += qp[g][k]*w.x + qp[g][k+1]*w.y + qp[g][k+2]*w.z + qp[g][k+3]*w.w;
    }
  }
  float m[G4], e[G4], s[G4];
  #pragma unroll
  for (int g = 0; g < G4; g++){ L[g] *= INV16; m[g] = wred_max(L[g]); }
  if ((t & 63) == 0)
    #pragma unroll
    for (int g = 0; g < G4; g++) redA[g][t >> 6] = m[g];
  __syncthreads();
  #pragma unroll
  for (int g = 0; g < G4; g++){
    m[g] = fmaxf(fmaxf(redA[g][0], redA[g][1]), fmaxf(redA[g][2], redA[g][3]));
    e[g] = __expf(L[g] - m[g]);
    s[g] = wred_sum(e[g]);
  }
  if ((t & 63) == 0)
    #pragma unroll
    for (int g = 0; g < G4; g++) redB2[g][t >> 6] = s[g];
  __syncthreads();
  #pragma unroll
  for (int g = 0; g < G4; g++){
    float ss = redB2[g][0] + redB2[g][1] + redB2[g][2] + redB2[g][3];
    float w = e[g] / ss;
    cwl[g][t] = w;
    cw_ws[(n0+g)*C_ + t] = w;
  }
  __syncthreads();
  if (t < R_){
    float qd[G4] = {0.f,0.f,0.f,0.f}, md[G4] = {0.f,0.f,0.f,0.f};
    const float* rrow = rcb + t*D_;
    const float* mrow = MT_f32 + t*C_;
    #pragma unroll 4
    for (int k = 0; k < D_; k += 4){
      float4 wv = *(const float4*)(rrow + k);
      float4 mv = *(const float4*)(mrow + k);
      #pragma unroll
      for (int g = 0; g < G4; g++){
        qd[g] += qp[g][k]*wv.x + qp[g][k+1]*wv.y + qp[g][k+2]*wv.z + qp[g][k+3]*wv.w;
        md[g] += cwl[g][k]*mv.x + cwl[g][k+1]*mv.y + cwl[g][k+2]*mv.z + cwl[g][k+3]*mv.w;
      }
    }
    #pragma unroll
    for (int g = 0; g < G4; g++){
      float Lr = (qd[g] - md[g]) * INV16;
      float mr = wred_max(Lr);
      float er = __expf(Lr - mr);
      float sr = wred_sum(er);
      rcw_ws[(n0+g)*R_ + t] = er / sr;
    }
  }
}

// ---------------- K2a: weights pass, 32-s tile, 4 blocks/CU, depth-2 A-prefetch
// block = (n, 32-s tile); 4 waves. Wave w owns: c-frags {w+4f} on both s-frags;
// r-frags {2*(w>>1), +1} on s-frag (w&1); matching MT frags for WM.
__global__ __launch_bounds__(256, 4) void k2a(const float* __restrict__ Kt,
    const ushortT* __restrict__ a1pk, const ushortT* __restrict__ mtpk,
    const float* __restrict__ cw_ws, const float* __restrict__ rcw_ws,
    const float* __restrict__ rlogit, float* __restrict__ comb_ws,
    float* __restrict__ out_ew)
{
  __shared__ __align__(16) ushortT Ktile[32*256];   // 16 KB
  __shared__ __align__(16) ushortT Wtile[32*256];   // 16 KB
  __shared__ float redS[4][32], redW[4][32];        // 1 KB (c-softmax)
  __shared__ float red3S[4][32], red3W[4][32];      // 1 KB (r-softmax)

  int bx  = blockIdx.x;
  int n   = bx >> 3;
  int s0  = (bx & 7) * 32;
  int tid = threadIdx.x;
  int lane = tid & 63, w = tid >> 6;
  int l15 = lane & 15, l4 = lane >> 4;
  int rp  = w >> 1;          // r-frag pair index (0..1)
  int sjr = w & 1;           // owned s-frag for R-side
  float gate  = 1.f / (1.f + __expf(-rlogit[0]));
  float inv1g = 1.f / (1.f + gate);

  const float* Kn = Kt + (size_t)n*S_*D_ + (size_t)s0*D_;

  // ---- stage K tile (32x256) fp32 -> bf16 swz LDS ----
  #pragma unroll
  for (int j = 0; j < 4; j++){
    int ch = tid + j*256;
    int row = ch >> 5, blk = ch & 31;
    const float* src = Kn + row*D_ + blk*8;
    float4 a = *(const float4*)src;
    float4 b = *(const float4*)(src + 4);
    uint4 wv = {packbf(a.x,a.y), packbf(a.z,a.w), packbf(b.x,b.y), packbf(b.z,b.w)};
    *(uint4*)((char*)Ktile + swz(row, blk*16)) = wv;
  }
  __syncthreads();                                   // B1

  // ---- GEMM1: accC[4 cf][2 sj] + accR[2 rf]; depth-2 A prefetch -------------
  const ushortT* a1b = a1pk + (size_t)lane*8;
  bf8 bnxC[4][2], bnxR[2][2];
  #pragma unroll
  for (int f = 0; f < 4; f++){
    bnxC[f][0] = *(const bf8*)(a1b + (size_t)((        w + 4*f)*64)*8);
    bnxC[f][1] = *(const bf8*)(a1b + (size_t)((20    + w + 4*f)*64)*8);
  }
  #pragma unroll
  for (int i = 0; i < 2; i++){
    bnxR[i][0] = *(const bf8*)(a1b + (size_t)((     16 + 2*rp + i)*64)*8);
    bnxR[i][1] = *(const bf8*)(a1b + (size_t)((20 + 16 + 2*rp + i)*64)*8);
  }
  f4 accC[4][2]; f4 accR[2];
  accR[0] = (f4)0.f; accR[1] = (f4)0.f;
  #pragma unroll
  for (int f = 0; f < 4; f++){ accC[f][0] = (f4)0.f; accC[f][1] = (f4)0.f; }
  #pragma unroll
  for (int ks = 0; ks < 8; ks++){
    bf8 kf0 = *(const bf8*)((const char*)Ktile + swz(     l15, ks*64 + l4*16));
    bf8 kf1 = *(const bf8*)((const char*)Ktile + swz(16 + l15, ks*64 + l4*16));
    bf8 kfr = sjr ? kf1 : kf0;
    #pragma unroll
    for (int f = 0; f < 4; f++){
      bf8 aC = bnxC[f][ks & 1];
      if (ks < 6)
        bnxC[f][ks & 1] = *(const bf8*)(a1b + (size_t)(((ks+2)*20 + w + 4*f)*64)*8);
      accC[f][0] = __builtin_amdgcn_mfma_f32_16x16x32_bf16(aC, kf0, accC[f][0], 0, 0, 0);
      accC[f][1] = __builtin_amdgcn_mfma_f32_16x16x32_bf16(aC, kf1, accC[f][1], 0, 0, 0);
    }
    #pragma unroll
    for (int i = 0; i < 2; i++){
      bf8 aR = bnxR[i][ks & 1];
      if (ks < 6)
        bnxR[i][ks & 1] = *(const bf8*)(a1b + (size_t)(((ks+2)*20 + 16 + 2*rp + i)*64)*8);
      accR[i] = __builtin_amdgcn_mfma_f32_16x16x32_bf16(aR, kfr, accR[i], 0, 0, 0);
    }
  }

  // ---- preload WM's first two MT frag-sets (hidden under exp phase) ---------
  const ushortT* mtb = mtpk + (size_t)lane*8;
  bf8 mnx[2][2];
  #pragma unroll
  for (int i = 0; i < 2; i++){
    mnx[i][0] = *(const bf8*)(mtb + (size_t)((    2*rp + i)*64)*8);
    mnx[i][1] = *(const bf8*)(mtb + (size_t)((4 + 2*rp + i)*64)*8);
  }

  // ---- softmax-c partials (exp in place, unnormalized) + Wexp write ---------
  float4 cwv[4];
  #pragma unroll
  for (int f = 0; f < 4; f++)
    cwv[f] = *(const float4*)(cw_ws + n*C_ + (w + 4*f)*16 + l4*4);
  float se[2] = {0,0}, sb[2] = {0,0};
  #pragma unroll
  for (int f = 0; f < 4; f++){
    int cbyte = ((w + 4*f)*16 + l4*4) * 2;
    #pragma unroll
    for (int sj = 0; sj < 2; sj++){
      float e0 = __expf(accC[f][sj][0] * INV16);
      float e1 = __expf(accC[f][sj][1] * INV16);
      float e2 = __expf(accC[f][sj][2] * INV16);
      float e3 = __expf(accC[f][sj][3] * INV16);
      se[sj] += (e0 + e1) + (e2 + e3);
      sb[sj] += e0*cwv[f].x + e1*cwv[f].y + e2*cwv[f].z + e3*cwv[f].w;
      int s_ = sj*16 + l15;
      *(uint32*)((char*)Wtile + swz(s_, cbyte))     = packbf(e0, e1);
      *(uint32*)((char*)Wtile + swz(s_, cbyte + 4)) = packbf(e2, e3);
    }
  }
  #pragma unroll
  for (int sj = 0; sj < 2; sj++){
    se[sj] += __shfl_xor(se[sj], 16); se[sj] += __shfl_xor(se[sj], 32);
    sb[sj] += __shfl_xor(sb[sj], 16); sb[sj] += __shfl_xor(sb[sj], 32);
  }
  if (l4 == 0){
    #pragma unroll
    for (int sj = 0; sj < 2; sj++){
      redS[w][sj*16 + l15] = se[sj];
      redW[w][sj*16 + l15] = sb[sj];
    }
  }
  __syncthreads();                                   // B2 (publishes Wexp + partials)

  float bw_q, rcp_q;
  {
    int sq = sjr*16 + l15;     // for writer waves (w<2) this is the owned col
    float sS = redS[0][sq] + redS[1][sq] + redS[2][sq] + redS[3][sq];
    float sW = redW[0][sq] + redW[1][sq] + redW[2][sq] + redW[3][sq];
    rcp_q = 1.f / sS;
    bw_q  = sW * rcp_q;
  }

  // ---- WM: MT frags {2rp,2rp+1} x Wexp[s-frag sjr]^T; depth-2 from L2 -------
  f4 wm[2]; wm[0] = (f4)0.f; wm[1] = (f4)0.f;
  #pragma unroll
  for (int ks = 0; ks < 8; ks++){
    bf8 wb = *(const bf8*)((const char*)Wtile + swz(sjr*16 + l15, ks*64 + l4*16));
    #pragma unroll
    for (int i = 0; i < 2; i++){
      bf8 a = mnx[i][ks & 1];
      if (ks < 6)
        mnx[i][ks & 1] = *(const bf8*)(mtb + (size_t)(((ks+2)*4 + 2*rp + i)*64)*8);
      wm[i] = __builtin_amdgcn_mfma_f32_16x16x32_bf16(a, wb, wm[i], 0, 0, 0);
    }
  }

  // ---- r-softmax partials: l3 = (accR - wm*rcp_q)/16 ------------------------
  float se3 = 0.f, sc3 = 0.f;
  #pragma unroll
  for (int i = 0; i < 2; i++){
    float4 rv = *(const float4*)(rcw_ws + n*R_ + (2*rp + i)*16 + l4*4);
    float e0 = __expf((accR[i][0] - wm[i][0]*rcp_q) * INV16);
    float e1 = __expf((accR[i][1] - wm[i][1]*rcp_q) * INV16);
    float e2 = __expf((accR[i][2] - wm[i][2]*rcp_q) * INV16);
    float e3 = __expf((accR[i][3] - wm[i][3]*rcp_q) * INV16);
    se3 += (e0 + e1) + (e2 + e3);
    sc3 += e0*rv.x + e1*rv.y + e2*rv.z + e3*rv.w;
  }
  se3 += __shfl_xor(se3, 16); se3 += __shfl_xor(se3, 32);
  sc3 += __shfl_xor(sc3, 16); sc3 += __shfl_xor(sc3, 32);
  if (l4 == 0){
    red3S[w][sjr*16 + l15] = se3;
    red3W[w][sjr*16 + l15] = sc3;
  }
  __syncthreads();                                   // B3

  // ---- combine r-halves + comb write (waves 0,1 own cols w*16+l15) ----------
  if (w < 2){
    int sq = w*16 + l15;
    float sS3 = red3S[w][sq] + red3S[w + 2][sq];
    float sW3 = red3W[w][sq] + red3W[w + 2][sq];
    float comb = bw_q + gate * (sW3 / sS3);
    if (l4 == 0){
      int sabs = n*S_ + s0 + sq;
      out_ew[sabs]  = comb * inv1g;
      comb_ws[sabs] = comb;
    }
  }
}

// ---------------- K2b: summary streaming pass (HBM-bound) ---------------------
__global__ __launch_bounds__(256) void k2b(const float* __restrict__ Vt,
    const float* __restrict__ comb_ws, float* __restrict__ sum_ws)
{
  __shared__ float cl[S_];
  __shared__ float4 part[4][64];
  int n = blockIdx.x, tid = threadIdx.x;
  int lane = tid & 63, w = tid >> 6;
  cl[tid] = comb_ws[n*S_ + tid];
  __syncthreads();
  const float* Vn = Vt + (size_t)n*S_*D_ + (size_t)(w*64)*D_ + lane*4;
  float4 a0 = {0,0,0,0}, a1 = {0,0,0,0};
  #pragma unroll 8
  for (int j = 0; j < 64; j += 2){
    float4 v0 = *(const float4*)(Vn + (size_t)j*D_);
    float4 v1 = *(const float4*)(Vn + (size_t)(j+1)*D_);
    float c0 = cl[w*64 + j], c1 = cl[w*64 + j + 1];
    a0.x = fmaf(c0, v0.x, a0.x); a0.y = fmaf(c0, v0.y, a0.y);
    a0.z = fmaf(c0, v0.z, a0.z); a0.w = fmaf(c0, v0.w, a0.w);
    a1.x = fmaf(c1, v1.x, a1.x); a1.y = fmaf(c1, v1.y, a1.y);
    a1.z = fmaf(c1, v1.z, a1.z); a1.w = fmaf(c1, v1.w, a1.w);
  }
  float4 acc = {a0.x+a1.x, a0.y+a1.y, a0.z+a1.z, a0.w+a1.w};
  part[w][lane] = acc;
  __syncthreads();
  if (tid < 64){
    float4 p0 = part[0][tid], p1 = part[1][tid], p2 = part[2][tid], p3 = part[3][tid];
    float4 r = {p0.x+p1.x+p2.x+p3.x, p0.y+p1.y+p2.y+p3.y,
                p0.z+p1.z+p2.z+p3.z, p0.w+p1.w+p2.w+p3.w};
    *(float4*)(sum_ws + (size_t)n*D_ + tid*4) = r;
  }
}

// ---------------- K3: readout GEMM (MFMA, bf16) --------------------------------
__global__ __launch_bounds__(256) void k3(const float* __restrict__ sum_ws,
    const ushortT* __restrict__ Wcr_bf, const float* __restrict__ bc,
    const float* __restrict__ br, float* __restrict__ out)
{
  __shared__ __align__(16) ushortT Stile[64*256];
  int bx = blockIdx.x;
  int ot = bx >> 4;
  int nt = bx & 15;
  int tid = threadIdx.x;
  int lane = tid & 63, wid = tid >> 6;
  int l15 = lane & 15, l4 = lane >> 4;

  const float* Sp = sum_ws + (size_t)nt*64*D_;
  #pragma unroll
  for (int j = 0; j < 8; j++){
    int ch = tid + j*256;
    int row = ch >> 5, blk = ch & 31;
    const float* src = Sp + row*D_ + blk*8;
    float4 a = *(const float4*)src;
    float4 b = *(const float4*)(src + 4);
    uint4 wv = {packbf(a.x,a.y), packbf(a.z,a.w), packbf(b.x,b.y), packbf(b.z,b.w)};
    *(uint4*)((char*)Stile + swz(row, blk*16)) = wv;
  }
  __syncthreads();

  int o0 = ot*64 + wid*16;
  const ushortT* Ap = Wcr_bf + (size_t)(o0 + l15)*D_ + l4*8;
  f4 acc[4];
  #pragma unroll
  for (int j = 0; j < 4; j++) acc[j] = (f4)0.f;
  #pragma unroll
  for (int k = 0; k < 8; k++){
    bf8 a = *(const bf8*)(Ap + k*32);
    #pragma unroll
    for (int nj = 0; nj < 4; nj++){
      bf8 b = *(const bf8*)((const char*)Stile + swz(nj*16 + l15, k*64 + l4*16));
      acc[nj] = __builtin_amdgcn_mfma_f32_16x16x32_bf16(a, b, acc[nj], 0, 0, 0);
    }
  }
  int obase = o0 + l4*4;
  if (obase < 1256){
    float4 bias;
    if (obase < CLS_) bias = *(const float4*)(bc + obase);
    else              bias = *(const float4*)(br + (obase - CLS_));
    #pragma unroll
    for (int nj = 0; nj < 4; nj++){
      int nn = nt*64 + nj*16 + l15;
      float4 v = {acc[nj][0]+bias.x, acc[nj][1]+bias.y, acc[nj][2]+bias.z, acc[nj][3]+bias.w};
      if (obase < CLS_) *(float4*)(out + (size_t)nn*CLS_ + obase) = v;
      else              *(float4*)(out + (size_t)N_*CLS_ + (size_t)nn*D_ + (obase - CLS_)) = v;
    }
  }
}

extern "C" void kernel_launch(void* const* d_in, const int* in_sizes, int n_in,
                              void* d_out, int out_size, void* d_ws, size_t ws_size,
                              hipStream_t stream)
{
  const float* q    = (const float*)d_in[0];
  const float* Kt   = (const float*)d_in[1];
  const float* Vt   = (const float*)d_in[2];
  const float* cb   = (const float*)d_in[3];
  const float* rcb  = (const float*)d_in[4];
  const float* Wq   = (const float*)d_in[5];
  const float* rlg  = (const float*)d_in[6];
  const float* Wc   = (const float*)d_in[7];
  const float* bc   = (const float*)d_in[8];
  const float* Wr   = (const float*)d_in[9];
  const float* br   = (const float*)d_in[10];
  float* out = (float*)d_out;
  float* ws  = (float*)d_ws;

  float* cw_ws   = ws;                          // N*C
  float* rcw_ws  = ws + 262144;                 // N*R
  float* sum_ws  = ws + 327680;                 // N*D
  float* comb_ws = ws + 589824;                 // N*S
  float* MT_f32  = ws + 851968;                 // R*C
  ushortT* a1pk   = (ushortT*)(ws + 868352);    // 320*D frag-packed
  ushortT* mtpk   = a1pk + (C_ + R_)*D_;        // R*C frag-packed
  ushortT* Wcr_bf = mtpk + R_*C_;               // 1280*D (Wc ; Wr ; zero pad)

  float* out_logits = out;
  float* out_ew     = out + (size_t)N_*CLS_ + (size_t)N_*D_;

  k0 <<<128,   256, 0, stream>>>(cb, rcb, Wc, Wr, a1pk, Wcr_bf, MT_f32, mtpk);
  k1 <<<N_/G4, 256, 0, stream>>>(q, cb, rcb, Wq, MT_f32, cw_ws, rcw_ws);
  k2a<<<N_*8,  256, 0, stream>>>(Kt, a1pk, mtpk, cw_ws, rcw_ws, rlg, comb_ws, out_ew);
  k2b<<<N_,    256, 0, stream>>>(Vt, comb_ws, sum_ws);
  k3 <<<320,   256, 0, stream>>>(sum_ws, Wcr_bf, bc, br, out_logits);
}

// Round 19
// 209.483 us; speedup vs baseline: 1.3557x; 1.0759x over previous
//
#include <hip/hip_runtime.h>
#include <hip/hip_bf16.h>
#include <math.h>

#define N_   1024
#define S_   256
#define D_   256
#define C_   256
#define R_   64
#define CLS_ 1000
#define INV16 0.0625f

typedef unsigned short ushortT;
typedef unsigned int uint32;
typedef short bf8 __attribute__((ext_vector_type(8)));
typedef float f4 __attribute__((ext_vector_type(4)));

static __device__ __forceinline__ float bf2f(uint32 u){
  return __uint_as_float(u << 16);
}
static __device__ __forceinline__ ushortT f2bf(float f){
  uint32 x = __float_as_uint(f);
  uint32 r = x + 0x7FFFu + ((x >> 16) & 1u);
  return (ushortT)(r >> 16);
}
static __device__ __forceinline__ uint32 packbf(float a, float b){
  return ((uint32)f2bf(b) << 16) | (uint32)f2bf(a);
}
static __device__ __forceinline__ float wred_max(float v){
  for (int o = 32; o; o >>= 1) v = fmaxf(v, __shfl_xor(v, o));
  return v;
}
static __device__ __forceinline__ float wred_sum(float v){
  for (int o = 32; o; o >>= 1) v += __shfl_xor(v, o);
  return v;
}
// swizzled byte offset inside a [rows][256]-bf16 LDS tile (row stride 512B)
static __device__ __forceinline__ int swz(int row, int colbyte){
  return row*512 + ((colbyte & ~15) ^ ((row & 7) << 4)) + (colbyte & 15);
}
// fragment-ready packed index for a [rows x 256] matrix, 16-row frags, K-step 32
static __device__ __forceinline__ int pkidx(int row, int col, int nfrag){
  int ks = col >> 5, hi = (col >> 3) & 3, e = col & 7;
  int frag = row >> 4, l15p = row & 15;
  return ((ks*nfrag + frag)*64 + hi*16 + l15p)*8 + e;
}

// ---------------- K0: weight prep + MT = cb @ rcb^T + sum_ws zero -------------
__global__ __launch_bounds__(256) void k0(const float* __restrict__ cb,
    const float* __restrict__ rcb, const float* __restrict__ Wc,
    const float* __restrict__ Wr, ushortT* __restrict__ a1pk,
    ushortT* __restrict__ Wcr_bf, float* __restrict__ MT_f32,
    ushortT* __restrict__ mtpk, float* __restrict__ sum_ws)
{
  __shared__ float rl[D_];
  int bid = blockIdx.x, t = threadIdx.x;
  int gtid = bid*256 + t;
  int stride = gridDim.x*256;
  for (int e = gtid; e < (C_ + R_)*D_; e += stride){
    int row = e >> 8, col = e & 255;
    float v = (row < C_) ? cb[e] : rcb[e - C_*D_];
    a1pk[pkidx(row, col, 20)] = f2bf(v);
  }
  for (int e = gtid; e < CLS_*D_; e += stride) Wcr_bf[e] = f2bf(Wc[e]);
  for (int e = gtid; e < D_*D_; e += stride)  Wcr_bf[CLS_*D_ + e] = f2bf(Wr[e]);
  for (int e = gtid; e < 24*D_; e += stride)  Wcr_bf[1256*D_ + e] = 0;
  for (int e = gtid; e < N_*D_; e += stride)  sum_ws[e] = 0.f;

  if (bid < R_){
    rl[t] = rcb[bid*D_ + t];
    __syncthreads();
    float acc = 0.f;
    const float* crow = cb + t*D_;
    #pragma unroll 8
    for (int k = 0; k < D_; k += 4){
      float4 w = *(const float4*)(crow + k);
      acc += w.x*rl[k] + w.y*rl[k+1] + w.z*rl[k+2] + w.w*rl[k+3];
    }
    MT_f32[bid*C_ + t] = acc;
    mtpk[pkidx(bid, t, 4)] = f2bf(acc);
  }
}

// ---------------- K1: per-query pass, batched x4 ------------------------------
#define G4 4
__global__ __launch_bounds__(256) void k1(const float* __restrict__ q,
    const float* __restrict__ cb, const float* __restrict__ rcb,
    const float* __restrict__ Wq, const float* __restrict__ MT_f32,
    float* __restrict__ cw_ws, float* __restrict__ rcw_ws)
{
  __shared__ float qv[G4][D_], qp[G4][D_], cwl[G4][C_];
  __shared__ float redA[G4][4], redB2[G4][4];
  int n0 = blockIdx.x*G4, t = threadIdx.x;
  #pragma unroll
  for (int g = 0; g < G4; g++) qv[g][t] = q[(n0+g)*D_ + t];
  __syncthreads();
  {
    float acc[G4] = {0.f,0.f,0.f,0.f};
    const float* wrow = Wq + t*D_;
    #pragma unroll 4
    for (int k = 0; k < D_; k += 4){
      float4 w = *(const float4*)(wrow + k);
      #pragma unroll
      for (int g = 0; g < G4; g++)
        acc[g] += qv[g][k]*w.x + qv[g][k+1]*w.y + qv[g][k+2]*w.z + qv[g][k+3]*w.w;
    }
    #pragma unroll
    for (int g = 0; g < G4; g++) qp[g][t] = acc[g];
  }
  __syncthreads();
  float L[G4] = {0.f,0.f,0.f,0.f};
  {
    const float* crow = cb + t*D_;
    #pragma unroll 4
    for (int k = 0; k < D_; k += 4){
      float4 w = *(const float4*)(crow + k);
      #pragma unroll
      for (int g = 0; g < G4; g++)
        L[g] += qp[g][k]*w.x + qp[g][k+1]*w.y + qp[g][k+2]*w.z + qp[g][k+3]*w.w;
    }
  }
  float m[G4], e[G4], s[G4];
  #pragma unroll
  for (int g = 0; g < G4; g++){ L[g] *= INV16; m[g] = wred_max(L[g]); }
  if ((t & 63) == 0)
    #pragma unroll
    for (int g = 0; g < G4; g++) redA[g][t >> 6] = m[g];
  __syncthreads();
  #pragma unroll
  for (int g = 0; g < G4; g++){
    m[g] = fmaxf(fmaxf(redA[g][0], redA[g][1]), fmaxf(redA[g][2], redA[g][3]));
    e[g] = __expf(L[g] - m[g]);
    s[g] = wred_sum(e[g]);
  }
  if ((t & 63) == 0)
    #pragma unroll
    for (int g = 0; g < G4; g++) redB2[g][t >> 6] = s[g];
  __syncthreads();
  #pragma unroll
  for (int g = 0; g < G4; g++){
    float ss = redB2[g][0] + redB2[g][1] + redB2[g][2] + redB2[g][3];
    float w = e[g] / ss;
    cwl[g][t] = w;
    cw_ws[(n0+g)*C_ + t] = w;
  }
  __syncthreads();
  if (t < R_){
    float qd[G4] = {0.f,0.f,0.f,0.f}, md[G4] = {0.f,0.f,0.f,0.f};
    const float* rrow = rcb + t*D_;
    const float* mrow = MT_f32 + t*C_;
    #pragma unroll 4
    for (int k = 0; k < D_; k += 4){
      float4 wv = *(const float4*)(rrow + k);
      float4 mv = *(const float4*)(mrow + k);
      #pragma unroll
      for (int g = 0; g < G4; g++){
        qd[g] += qp[g][k]*wv.x + qp[g][k+1]*wv.y + qp[g][k+2]*wv.z + qp[g][k+3]*wv.w;
        md[g] += cwl[g][k]*mv.x + cwl[g][k+1]*mv.y + cwl[g][k+2]*mv.z + cwl[g][k+3]*mv.w;
      }
    }
    #pragma unroll
    for (int g = 0; g < G4; g++){
      float Lr = (qd[g] - md[g]) * INV16;
      float mr = wred_max(Lr);
      float er = __expf(Lr - mr);
      float sr = wred_sum(er);
      rcw_ws[(n0+g)*R_ + t] = er / sr;
    }
  }
}

// ---------------- K2a: weights + fused V, block-reduced atomics ---------------
// block = (n, 32-s tile); 4 waves. Wave w owns: c-frags {w+4f} on both s-frags;
// r-frags {2*(w>>1), +1} on s-frag (w&1); matching MT frags for WM.
// V: each wave streams rows [w*8,+8), block-reduces via Ktile overlay, then
// ONE wave atomically adds (8 writers/dword per n, vs R17's 32).
__global__ __launch_bounds__(256, 4) void k2a(const float* __restrict__ Kt,
    const float* __restrict__ Vt, const ushortT* __restrict__ a1pk,
    const ushortT* __restrict__ mtpk, const float* __restrict__ cw_ws,
    const float* __restrict__ rcw_ws, const float* __restrict__ rlogit,
    float* __restrict__ sum_ws, float* __restrict__ out_ew)
{
  __shared__ __align__(16) ushortT Ktile[32*256];   // 16 KB (V-partial overlay at end)
  __shared__ __align__(16) ushortT Wtile[32*256];   // 16 KB
  __shared__ float redS[4][32], redW[4][32];        // 1 KB (c-softmax)
  __shared__ float red3S[4][32], red3W[4][32];      // 1 KB (r-softmax)
  __shared__ float combl[32];

  int bx  = blockIdx.x;
  int n   = bx >> 3;
  int s0  = (bx & 7) * 32;
  int tid = threadIdx.x;
  int lane = tid & 63, w = tid >> 6;
  int l15 = lane & 15, l4 = lane >> 4;
  int rp  = w >> 1;          // r-frag pair index (0..1)
  int sjr = w & 1;           // owned s-frag for R-side
  float gate  = 1.f / (1.f + __expf(-rlogit[0]));
  float inv1g = 1.f / (1.f + gate);

  const float* Kn = Kt + (size_t)n*S_*D_ + (size_t)s0*D_;

  // ---- stage K tile (32x256) fp32 -> bf16 swz LDS ----
  #pragma unroll
  for (int j = 0; j < 4; j++){
    int ch = tid + j*256;
    int row = ch >> 5, blk = ch & 31;
    const float* src = Kn + row*D_ + blk*8;
    float4 a = *(const float4*)src;
    float4 b = *(const float4*)(src + 4);
    uint4 wv = {packbf(a.x,a.y), packbf(a.z,a.w), packbf(b.x,b.y), packbf(b.z,b.w)};
    *(uint4*)((char*)Ktile + swz(row, blk*16)) = wv;
  }
  __syncthreads();                                   // B1

  // ---- GEMM1: accC[4 cf][2 sj] + accR[2 rf]; depth-2 A prefetch -------------
  const ushortT* a1b = a1pk + (size_t)lane*8;
  bf8 bnxC[4][2], bnxR[2][2];
  #pragma unroll
  for (int f = 0; f < 4; f++){
    bnxC[f][0] = *(const bf8*)(a1b + (size_t)((        w + 4*f)*64)*8);
    bnxC[f][1] = *(const bf8*)(a1b + (size_t)((20    + w + 4*f)*64)*8);
  }
  #pragma unroll
  for (int i = 0; i < 2; i++){
    bnxR[i][0] = *(const bf8*)(a1b + (size_t)((     16 + 2*rp + i)*64)*8);
    bnxR[i][1] = *(const bf8*)(a1b + (size_t)((20 + 16 + 2*rp + i)*64)*8);
  }
  f4 accC[4][2]; f4 accR[2];
  accR[0] = (f4)0.f; accR[1] = (f4)0.f;
  #pragma unroll
  for (int f = 0; f < 4; f++){ accC[f][0] = (f4)0.f; accC[f][1] = (f4)0.f; }
  #pragma unroll
  for (int ks = 0; ks < 8; ks++){
    bf8 kf0 = *(const bf8*)((const char*)Ktile + swz(     l15, ks*64 + l4*16));
    bf8 kf1 = *(const bf8*)((const char*)Ktile + swz(16 + l15, ks*64 + l4*16));
    bf8 kfr = sjr ? kf1 : kf0;
    #pragma unroll
    for (int f = 0; f < 4; f++){
      bf8 aC = bnxC[f][ks & 1];
      if (ks < 6)
        bnxC[f][ks & 1] = *(const bf8*)(a1b + (size_t)(((ks+2)*20 + w + 4*f)*64)*8);
      accC[f][0] = __builtin_amdgcn_mfma_f32_16x16x32_bf16(aC, kf0, accC[f][0], 0, 0, 0);
      accC[f][1] = __builtin_amdgcn_mfma_f32_16x16x32_bf16(aC, kf1, accC[f][1], 0, 0, 0);
    }
    #pragma unroll
    for (int i = 0; i < 2; i++){
      bf8 aR = bnxR[i][ks & 1];
      if (ks < 6)
        bnxR[i][ks & 1] = *(const bf8*)(a1b + (size_t)(((ks+2)*20 + 16 + 2*rp + i)*64)*8);
      accR[i] = __builtin_amdgcn_mfma_f32_16x16x32_bf16(aR, kfr, accR[i], 0, 0, 0);
    }
  }

  // ---- preload WM's first two MT frag-sets (hidden under exp phase) ---------
  const ushortT* mtb = mtpk + (size_t)lane*8;
  bf8 mnx[2][2];
  #pragma unroll
  for (int i = 0; i < 2; i++){
    mnx[i][0] = *(const bf8*)(mtb + (size_t)((    2*rp + i)*64)*8);
    mnx[i][1] = *(const bf8*)(mtb + (size_t)((4 + 2*rp + i)*64)*8);
  }

  // ---- softmax-c partials (exp in place, unnormalized) + Wexp write ---------
  float4 cwv[4];
  #pragma unroll
  for (int f = 0; f < 4; f++)
    cwv[f] = *(const float4*)(cw_ws + n*C_ + (w + 4*f)*16 + l4*4);
  float se[2] = {0,0}, sb[2] = {0,0};
  #pragma unroll
  for (int f = 0; f < 4; f++){
    int cbyte = ((w + 4*f)*16 + l4*4) * 2;
    #pragma unroll
    for (int sj = 0; sj < 2; sj++){
      float e0 = __expf(accC[f][sj][0] * INV16);
      float e1 = __expf(accC[f][sj][1] * INV16);
      float e2 = __expf(accC[f][sj][2] * INV16);
      float e3 = __expf(accC[f][sj][3] * INV16);
      se[sj] += (e0 + e1) + (e2 + e3);
      sb[sj] += e0*cwv[f].x + e1*cwv[f].y + e2*cwv[f].z + e3*cwv[f].w;
      int s_ = sj*16 + l15;
      *(uint32*)((char*)Wtile + swz(s_, cbyte))     = packbf(e0, e1);
      *(uint32*)((char*)Wtile + swz(s_, cbyte + 4)) = packbf(e2, e3);
    }
  }
  #pragma unroll
  for (int sj = 0; sj < 2; sj++){
    se[sj] += __shfl_xor(se[sj], 16); se[sj] += __shfl_xor(se[sj], 32);
    sb[sj] += __shfl_xor(sb[sj], 16); sb[sj] += __shfl_xor(sb[sj], 32);
  }
  if (l4 == 0){
    #pragma unroll
    for (int sj = 0; sj < 2; sj++){
      redS[w][sj*16 + l15] = se[sj];
      redW[w][sj*16 + l15] = sb[sj];
    }
  }
  __syncthreads();                                   // B2 (publishes Wexp + partials)

  float bw_q, rcp_q;
  {
    int sq = sjr*16 + l15;     // for writer waves (w<2) this is the owned col
    float sS = redS[0][sq] + redS[1][sq] + redS[2][sq] + redS[3][sq];
    float sW = redW[0][sq] + redW[1][sq] + redW[2][sq] + redW[3][sq];
    rcp_q = 1.f / sS;
    bw_q  = sW * rcp_q;
  }

  // ---- WM: MT frags {2rp,2rp+1} x Wexp[s-frag sjr]^T; depth-2 from L2 -------
  f4 wm[2]; wm[0] = (f4)0.f; wm[1] = (f4)0.f;
  #pragma unroll
  for (int ks = 0; ks < 8; ks++){
    bf8 wb = *(const bf8*)((const char*)Wtile + swz(sjr*16 + l15, ks*64 + l4*16));
    #pragma unroll
    for (int i = 0; i < 2; i++){
      bf8 a = mnx[i][ks & 1];
      if (ks < 6)
        mnx[i][ks & 1] = *(const bf8*)(mtb + (size_t)(((ks+2)*4 + 2*rp + i)*64)*8);
      wm[i] = __builtin_amdgcn_mfma_f32_16x16x32_bf16(a, wb, wm[i], 0, 0, 0);
    }
  }

  // ---- r-softmax partials: l3 = (accR - wm*rcp_q)/16 ------------------------
  float se3 = 0.f, sc3 = 0.f;
  #pragma unroll
  for (int i = 0; i < 2; i++){
    float4 rv = *(const float4*)(rcw_ws + n*R_ + (2*rp + i)*16 + l4*4);
    float e0 = __expf((accR[i][0] - wm[i][0]*rcp_q) * INV16);
    float e1 = __expf((accR[i][1] - wm[i][1]*rcp_q) * INV16);
    float e2 = __expf((accR[i][2] - wm[i][2]*rcp_q) * INV16);
    float e3 = __expf((accR[i][3] - wm[i][3]*rcp_q) * INV16);
    se3 += (e0 + e1) + (e2 + e3);
    sc3 += e0*rv.x + e1*rv.y + e2*rv.z + e3*rv.w;
  }
  se3 += __shfl_xor(se3, 16); se3 += __shfl_xor(se3, 32);
  sc3 += __shfl_xor(sc3, 16); sc3 += __shfl_xor(sc3, 32);
  if (l4 == 0){
    red3S[w][sjr*16 + l15] = se3;
    red3W[w][sjr*16 + l15] = sc3;
  }
  __syncthreads();                                   // B3

  // ---- combine r-halves + comb write (waves 0,1 own cols w*16+l15) ----------
  if (w < 2){
    int sq = w*16 + l15;
    float sS3 = red3S[w][sq] + red3S[w + 2][sq];
    float sW3 = red3W[w][sq] + red3W[w + 2][sq];
    float comb = bw_q + gate * (sW3 / sS3);
    if (l4 == 0){
      int sabs = n*S_ + s0 + sq;
      out_ew[sabs] = comb * inv1g;
      combl[sq]    = comb;
    }
  }
  __syncthreads();                                   // B4 (combl ready)

  // ---- fused V summary: wave w streams rows [w*8,+8); block-reduce ----------
  {
    const float* vp = Vt + (size_t)n*S_*D_ + (size_t)(s0 + w*8)*D_ + lane*4;
    float4 sacc = {0.f, 0.f, 0.f, 0.f};
    #pragma unroll
    for (int j = 0; j < 8; j++){
      float c = combl[w*8 + j];
      float4 v = *(const float4*)(vp + (size_t)j*D_);
      sacc.x = fmaf(c, v.x, sacc.x); sacc.y = fmaf(c, v.y, sacc.y);
      sacc.z = fmaf(c, v.z, sacc.z); sacc.w = fmaf(c, v.w, sacc.w);
    }
    float4* sred = (float4*)Ktile;       // Ktile dead after GEMM1; [4][64] float4
    sred[w*64 + lane] = sacc;
  }
  __syncthreads();                                   // B5
  if (tid < 64){
    float4 a0 = ((float4*)Ktile)[tid],       a1 = ((float4*)Ktile)[64 + tid];
    float4 a2 = ((float4*)Ktile)[128 + tid], a3 = ((float4*)Ktile)[192 + tid];
    float* dst = sum_ws + (size_t)n*D_ + tid*4;
    atomicAdd(dst + 0, a0.x + a1.x + a2.x + a3.x);
    atomicAdd(dst + 1, a0.y + a1.y + a2.y + a3.y);
    atomicAdd(dst + 2, a0.z + a1.z + a2.z + a3.z);
    atomicAdd(dst + 3, a0.w + a1.w + a2.w + a3.w);
  }
}

// ---------------- K3: readout GEMM (MFMA, bf16) --------------------------------
__global__ __launch_bounds__(256) void k3(const float* __restrict__ sum_ws,
    const ushortT* __restrict__ Wcr_bf, const float* __restrict__ bc,
    const float* __restrict__ br, float* __restrict__ out)
{
  __shared__ __align__(16) ushortT Stile[64*256];
  int bx = blockIdx.x;
  int ot = bx >> 4;
  int nt = bx & 15;
  int tid = threadIdx.x;
  int lane = tid & 63, wid = tid >> 6;
  int l15 = lane & 15, l4 = lane >> 4;

  const float* Sp = sum_ws + (size_t)nt*64*D_;
  #pragma unroll
  for (int j = 0; j < 8; j++){
    int ch = tid + j*256;
    int row = ch >> 5, blk = ch & 31;
    const float* src = Sp + row*D_ + blk*8;
    float4 a = *(const float4*)src;
    float4 b = *(const float4*)(src + 4);
    uint4 wv = {packbf(a.x,a.y), packbf(a.z,a.w), packbf(b.x,b.y), packbf(b.z,b.w)};
    *(uint4*)((char*)Stile + swz(row, blk*16)) = wv;
  }
  __syncthreads();

  int o0 = ot*64 + wid*16;
  const ushortT* Ap = Wcr_bf + (size_t)(o0 + l15)*D_ + l4*8;
  f4 acc[4];
  #pragma unroll
  for (int j = 0; j < 4; j++) acc[j] = (f4)0.f;
  #pragma unroll
  for (int k = 0; k < 8; k++){
    bf8 a = *(const bf8*)(Ap + k*32);
    #pragma unroll
    for (int nj = 0; nj < 4; nj++){
      bf8 b = *(const bf8*)((const char*)Stile + swz(nj*16 + l15, k*64 + l4*16));
      acc[nj] = __builtin_amdgcn_mfma_f32_16x16x32_bf16(a, b, acc[nj], 0, 0, 0);
    }
  }
  int obase = o0 + l4*4;
  if (obase < 1256){
    float4 bias;
    if (obase < CLS_) bias = *(const float4*)(bc + obase);
    else              bias = *(const float4*)(br + (obase - CLS_));
    #pragma unroll
    for (int nj = 0; nj < 4; nj++){
      int nn = nt*64 + nj*16 + l15;
      float4 v = {acc[nj][0]+bias.x, acc[nj][1]+bias.y, acc[nj][2]+bias.z, acc[nj][3]+bias.w};
      if (obase < CLS_) *(float4*)(out + (size_t)nn*CLS_ + obase) = v;
      else              *(float4*)(out + (size_t)N_*CLS_ + (size_t)nn*D_ + (obase - CLS_)) = v;
    }
  }
}

extern "C" void kernel_launch(void* const* d_in, const int* in_sizes, int n_in,
                              void* d_out, int out_size, void* d_ws, size_t ws_size,
                              hipStream_t stream)
{
  const float* q    = (const float*)d_in[0];
  const float* Kt   = (const float*)d_in[1];
  const float* Vt   = (const float*)d_in[2];
  const float* cb   = (const float*)d_in[3];
  const float* rcb  = (const float*)d_in[4];
  const float* Wq   = (const float*)d_in[5];
  const float* rlg  = (const float*)d_in[6];
  const float* Wc   = (const float*)d_in[7];
  const float* bc   = (const float*)d_in[8];
  const float* Wr   = (const float*)d_in[9];
  const float* br   = (const float*)d_in[10];
  float* out = (float*)d_out;
  float* ws  = (float*)d_ws;

  float* cw_ws   = ws;                          // N*C
  float* rcw_ws  = ws + 262144;                 // N*R
  float* sum_ws  = ws + 327680;                 // N*D
  float* MT_f32  = ws + 851968;                 // R*C
  ushortT* a1pk   = (ushortT*)(ws + 868352);    // 320*D frag-packed
  ushortT* mtpk   = a1pk + (C_ + R_)*D_;        // R*C frag-packed
  ushortT* Wcr_bf = mtpk + R_*C_;               // 1280*D (Wc ; Wr ; zero pad)

  float* out_logits = out;
  float* out_ew     = out + (size_t)N_*CLS_ + (size_t)N_*D_;

  k0 <<<128,   256, 0, stream>>>(cb, rcb, Wc, Wr, a1pk, Wcr_bf, MT_f32, mtpk, sum_ws);
  k1 <<<N_/G4, 256, 0, stream>>>(q, cb, rcb, Wq, MT_f32, cw_ws, rcw_ws);
  k2a<<<N_*8,  256, 0, stream>>>(Kt, Vt, a1pk, mtpk, cw_ws, rcw_ws, rlg, sum_ws, out_ew);
  k3 <<<320,   256, 0, stream>>>(sum_ws, Wcr_bf, bc, br, out_logits);
}